// Round 2
// baseline (316.776 us; speedup 1.0000x reference)
//
#include <hip/hip_runtime.h>
#include <hip/hip_bf16.h>

#define DHALF 0.05f   // DT/2
#define DT_F  0.1f

// One block per channel d. Computes K[d][k] = Cv . A_bar^k . B_bar, k=0..63.
// M = I - 0.05*A (diag ~4.2, offdiag <=0.05 in magnitude) -> LU w/o pivoting.
__global__ __launch_bounds__(256) void s4_discretize(
    const float* __restrict__ Ag,   // (128,64,64)
    const float* __restrict__ Bg,   // (128,64,1)
    const float* __restrict__ Cg,   // (128,1,64)
    float* __restrict__ Kout)       // (128,64) fp32
{
  __shared__ float M[64][65];   // LU in place
  __shared__ float X[64][67];   // 65 RHS: cols 0..63 = I+0.05A, col 64 = B
  __shared__ float V[64][65];   // impulse vectors v_k
  __shared__ float Cs[64];
  __shared__ float P[4][64];    // matvec partials

  const int d   = blockIdx.x;
  const int tid = threadIdx.x;
  const int r   = tid >> 6;     // 0..3 (wave id)
  const int c   = tid & 63;     // lane

  // init
  for (int idx = tid; idx < 4096; idx += 256) {
    int i = idx >> 6, j = idx & 63;
    float a = Ag[(size_t)d * 4096 + idx];
    float e = (i == j) ? 1.f : 0.f;
    M[i][j] = e - DHALF * a;
    X[i][j] = e + DHALF * a;
  }
  if (tid < 64) {
    X[tid][64] = Bg[d * 64 + tid];
    Cs[tid]    = Cg[d * 64 + tid];
  }
  __syncthreads();

  // LU (Doolittle, unit lower, no pivoting)
  for (int k = 0; k < 63; ++k) {
    if (r == 0 && c > k) M[c][k] /= M[k][k];
    __syncthreads();
    for (int i = k + 1 + r; i < 64; i += 4)
      if (c > k) M[i][c] -= M[i][k] * M[k][c];
    __syncthreads();
  }

  // forward substitution, 65 RHS; lane c owns col c (c==0 also col 64)
  for (int i = 0; i < 63; ++i) {
    for (int m = i + 1 + r; m < 64; m += 4) {
      float li = M[m][i];
      X[m][c] -= li * X[i][c];
      if (c == 0) X[m][64] -= li * X[i][64];
    }
    __syncthreads();
  }

  // back substitution
  for (int i = 63; i >= 0; --i) {
    if (r == 0) {
      float inv = 1.f / M[i][i];
      X[i][c] *= inv;
      if (c == 0) X[i][64] *= inv;
    }
    __syncthreads();
    for (int m = r; m < i; m += 4) {
      float ui = M[m][i];
      X[m][c] -= ui * X[i][c];
      if (c == 0) X[m][64] -= ui * X[i][64];
    }
    __syncthreads();
  }
  // Now X[:,0:64] = A_bar, X[:,64] = M^{-1} B

  // impulse response: v_0 = B_bar = DT * M^{-1} B ; v_{k+1} = A_bar v_k
  if (tid < 64) V[0][tid] = X[tid][64] * DT_F;
  __syncthreads();
  for (int k = 1; k < 64; ++k) {
    float p = 0.f;
    const int n0 = r * 16;
    #pragma unroll
    for (int n = 0; n < 16; ++n)
      p += X[c][n0 + n] * V[k - 1][n0 + n];
    P[r][c] = p;
    __syncthreads();
    if (r == 0) V[k][c] = P[0][c] + P[1][c] + P[2][c] + P[3][c];
    __syncthreads();
  }

  // K[d][k] = Cv . v_k  (thread k does one dot)
  if (tid < 64) {
    float s = 0.f;
    #pragma unroll
    for (int n = 0; n < 64; ++n) s += Cs[n] * V[tid][n];
    Kout[d * 64 + tid] = s;
  }
}

// Depthwise causal conv, T=64 taps. Block = (128 d, 2 chunks); thread does 32 t.
__global__ __launch_bounds__(256) void s4_conv(
    const float* __restrict__ xg,   // (16,4096,128)
    const float* __restrict__ Kg,   // (128,64)
    float* __restrict__ yg)         // (16,4096,128)
{
  __shared__ float Klds[128 * 65]; // pad 65: lane d reads bank (d*65+k)%32 -> conflict-light
  const int tid = threadIdx.y * 128 + threadIdx.x;
  for (int idx = tid; idx < 8192; idx += 256)
    Klds[(idx >> 6) * 65 + (idx & 63)] = Kg[idx];
  __syncthreads();

  const int d  = threadIdx.x;
  const int b  = blockIdx.y;
  const int t0 = blockIdx.x * 64 + threadIdx.y * 32;

  const float* xb = xg + (size_t)b * 4096 * 128 + d;

  float w[95];
  #pragma unroll
  for (int i = 0; i < 95; ++i) {
    int t = t0 - 63 + i;
    w[i] = (t >= 0) ? xb[(size_t)t * 128] : 0.f;
  }

  float acc[32];
  #pragma unroll
  for (int t = 0; t < 32; ++t) acc[t] = 0.f;

  const float* Kd = &Klds[d * 65];
  #pragma unroll
  for (int k = 0; k < 64; ++k) {
    float kv = Kd[k];
    #pragma unroll
    for (int t = 0; t < 32; ++t)
      acc[t] += kv * w[t + 63 - k];
  }

  float* yb = yg + ((size_t)b * 4096 + t0) * 128 + d;
  #pragma unroll
  for (int t = 0; t < 32; ++t)
    yb[(size_t)t * 128] = acc[t];
}

extern "C" void kernel_launch(void* const* d_in, const int* in_sizes, int n_in,
                              void* d_out, int out_size, void* d_ws, size_t ws_size,
                              hipStream_t stream) {
  const float* x = (const float*)d_in[0];
  const float* A = (const float*)d_in[1];
  const float* B = (const float*)d_in[2];
  const float* C = (const float*)d_in[3];
  float* y = (float*)d_out;
  float* K = (float*)d_ws;   // 128*64*4 = 32 KB scratch

  s4_discretize<<<128, 256, 0, stream>>>(A, B, C, K);
  dim3 grid(64, 16), block(128, 2);
  s4_conv<<<grid, block, 0, stream>>>(x, K, y);
}

// Round 3
// 134.142 us; speedup vs baseline: 2.3615x; 2.3615x over previous
//
#include <hip/hip_runtime.h>

typedef float f4 __attribute__((ext_vector_type(4)));

#define PAD 68          // row stride for 64x64 LDS matrices: keeps 16B align, banks (4i+j)%32
#define ALPHA 0.30f     // ~2/(lmin+lmax) for M = 4.2I - 0.05U

// acc[m*4+c] = sum_n L[i0+m][n] * R[n][j0+c]   (row stride PAD)
__device__ __forceinline__ void mm_acc(const float* L, const float* R,
                                       int i0, int j0, float acc[16]) {
  #pragma unroll
  for (int m = 0; m < 16; ++m) acc[m] = 0.f;
  #pragma unroll
  for (int n = 0; n < 64; n += 4) {
    f4 La[4], Rb[4];
    #pragma unroll
    for (int m = 0; m < 4; ++m) La[m] = *(const f4*)&L[(i0 + m) * PAD + n];
    #pragma unroll
    for (int p = 0; p < 4; ++p) Rb[p] = *(const f4*)&R[(n + p) * PAD + j0];
    #pragma unroll
    for (int m = 0; m < 4; ++m)
      #pragma unroll
      for (int p = 0; p < 4; ++p)
        #pragma unroll
        for (int c = 0; c < 4; ++c)
          acc[m * 4 + c] += La[m][p] * Rb[p][c];
  }
}

// One block per channel d. K[k] = Cv . A_bar^k . B_bar via Newton inverse + power doubling.
// Writes K TRANSPOSED: Kout[k*128 + d].
__global__ __launch_bounds__(256) void s4_discretize(
    const float* __restrict__ Ag,   // (128,64,64)
    const float* __restrict__ Bg,   // (128,64)
    const float* __restrict__ Cg,   // (128,64)
    float* __restrict__ Kout)       // (64,128)
{
  __shared__ float Ms[64 * PAD];    // M, later A_bar
  __shared__ float Xs[64 * PAD];    // Newton iterate -> M^-1, later A_bar^4
  __shared__ float Ts[64 * PAD];    // temp, later A_bar^2
  __shared__ float C4[4][65];       // Cv . A_bar^j
  __shared__ float U16[64][16];     // A4^i . B_bar
  __shared__ float Bv[64], Cv0[64], Bb[64];
  __shared__ float Pr[4][64];

  const int d   = blockIdx.x;
  const int tid = threadIdx.x;
  const int i0  = (tid >> 4) << 2;  // output row tile
  const int j0  = (tid & 15) << 2;  // output col tile
  const int q   = tid >> 6;         // wave id 0..3
  const int ln  = tid & 63;

  // ---- load, build M = I - 0.05A and X1 = 2aI - a^2 M ----
  for (int idx = tid; idx < 4096; idx += 256) {
    int i = idx >> 6, j = idx & 63;
    float a = Ag[(size_t)d * 4096 + idx];
    float m = ((i == j) ? 1.f : 0.f) - 0.05f * a;
    Ms[i * PAD + j] = m;
    Xs[i * PAD + j] = ((i == j) ? 2.f * ALPHA : 0.f) - ALPHA * ALPHA * m;
  }
  if (tid < 64) { Bv[tid] = Bg[d * 64 + tid]; Cv0[tid] = Cg[d * 64 + tid]; }
  __syncthreads();

  // ---- 3 Newton iterations: X <- 2X - X(MX) ----
  float acc[16];
  for (int it = 0; it < 3; ++it) {
    mm_acc(Ms, Xs, i0, j0, acc);                // T = M X
    #pragma unroll
    for (int m = 0; m < 4; ++m) {
      f4 t = {acc[m*4+0], acc[m*4+1], acc[m*4+2], acc[m*4+3]};
      *(f4*)&Ts[(i0 + m) * PAD + j0] = t;
    }
    __syncthreads();
    mm_acc(Xs, Ts, i0, j0, acc);                // X T
    __syncthreads();                            // all reads of X done
    #pragma unroll
    for (int m = 0; m < 4; ++m) {
      f4 xo = *(const f4*)&Xs[(i0 + m) * PAD + j0];
      f4 t = {acc[m*4+0], acc[m*4+1], acc[m*4+2], acc[m*4+3]};
      *(f4*)&Xs[(i0 + m) * PAD + j0] = 2.f * xo - t;
    }
    __syncthreads();
  }
  // Xs = M^-1 (resid ~7e-9)

  // ---- B_bar = 0.1 * X Bv ; A_bar = 2X - I -> Ms ----
  {
    float p = 0.f;
    #pragma unroll
    for (int m = 0; m < 16; ++m) p += Xs[ln * PAD + q * 16 + m] * Bv[q * 16 + m];
    Pr[q][ln] = p;
  }
  for (int idx = tid; idx < 4096; idx += 256) {
    int i = idx >> 6, j = idx & 63;
    Ms[i * PAD + j] = 2.f * Xs[i * PAD + j] - ((i == j) ? 1.f : 0.f);
  }
  __syncthreads();
  if (tid < 64) Bb[tid] = 0.1f * (Pr[0][tid] + Pr[1][tid] + Pr[2][tid] + Pr[3][tid]);
  __syncthreads();

  // ---- C chain: c_j = Cv . A_bar^j, j=0..3 ----
  if (tid < 64) C4[0][tid] = Cv0[tid];
  __syncthreads();
  for (int j = 1; j < 4; ++j) {
    float p = 0.f;
    #pragma unroll
    for (int m = 0; m < 16; ++m) p += C4[j - 1][q * 16 + m] * Ms[(q * 16 + m) * PAD + ln];
    Pr[q][ln] = p;
    __syncthreads();
    if (q == 0) C4[j][ln] = Pr[0][ln] + Pr[1][ln] + Pr[2][ln] + Pr[3][ln];
    __syncthreads();
  }

  // ---- A^2 -> Ts ; A^4 -> Xs ----
  mm_acc(Ms, Ms, i0, j0, acc);
  #pragma unroll
  for (int m = 0; m < 4; ++m) {
    f4 t = {acc[m*4+0], acc[m*4+1], acc[m*4+2], acc[m*4+3]};
    *(f4*)&Ts[(i0 + m) * PAD + j0] = t;
  }
  __syncthreads();
  mm_acc(Ts, Ts, i0, j0, acc);
  __syncthreads();                              // Xs reads (none pending) / Ts reads done
  #pragma unroll
  for (int m = 0; m < 4; ++m) {
    f4 t = {acc[m*4+0], acc[m*4+1], acc[m*4+2], acc[m*4+3]};
    *(f4*)&Xs[(i0 + m) * PAD + j0] = t;
  }
  __syncthreads();

  // ---- U chain: u_i = A4^i . B_bar, i=0..15 ----
  if (tid < 64) U16[tid][0] = Bb[tid];
  __syncthreads();
  for (int i = 1; i < 16; ++i) {
    float p = 0.f;
    #pragma unroll
    for (int m = 0; m < 16; ++m) p += Xs[ln * PAD + q * 16 + m] * U16[q * 16 + m][i - 1];
    Pr[q][ln] = p;
    __syncthreads();
    if (q == 0) U16[ln][i] = Pr[0][ln] + Pr[1][ln] + Pr[2][ln] + Pr[3][ln];
    __syncthreads();
  }

  // ---- K[k] = c_{k&3} . u_{k>>2}, write transposed ----
  if (tid < 64) {
    int i = tid >> 2, j = tid & 3;
    float s = 0.f;
    #pragma unroll
    for (int n = 0; n < 64; ++n) s += C4[j][n] * U16[n][i];
    Kout[tid * 128 + d] = s;
  }
}

// Depthwise causal conv, 64 taps. Block: 64 d x 128 t tile; thread = (dl, g) does 32 t.
__global__ __launch_bounds__(256) void s4_conv(
    const float* __restrict__ xg,   // (16,4096,128)
    const float* __restrict__ Ktg,  // (64,128) transposed K
    float* __restrict__ yg)         // (16,4096,128)
{
  __shared__ float xs[191 * 64];    // 48,896 B
  __shared__ float Ks[64 * 64];     // 16,384 B  (total 65,280 <= 64 KiB)

  const int tid = threadIdx.y * 64 + threadIdx.x;
  const int tc  = blockIdx.x;       // t chunk (128 t each)
  const int dh  = blockIdx.y;       // d half
  const int b   = blockIdx.z;
  const int d0  = dh * 64;
  const int t0  = tc * 128;

  // stage K half: Ks[k*64+dl] = Kt[k][d0+dl]
  for (int idx = tid; idx < 4096; idx += 256)
    Ks[idx] = Ktg[(idx >> 6) * 128 + d0 + (idx & 63)];

  // stage x rows t0-63 .. t0+127 (191 rows x 64 floats), float4 coalesced
  const float* xb = xg + (size_t)b * 4096 * 128 + d0;
  for (int idx = tid; idx < 191 * 16; idx += 256) {
    int row = idx >> 4, c4 = (idx & 15) << 2;
    int t = t0 - 63 + row;
    f4 v = {0.f, 0.f, 0.f, 0.f};
    if (t >= 0) v = *(const f4*)&xb[(size_t)t * 128 + c4];
    *(f4*)&xs[row * 64 + c4] = v;
  }
  __syncthreads();

  const int dl = threadIdx.x;
  const int g  = threadIdx.y;

  float acc[32];
  #pragma unroll
  for (int t = 0; t < 32; ++t) acc[t] = 0.f;

  float w[47];
  #pragma unroll
  for (int k0 = 0; k0 < 64; k0 += 16) {
    const int base = g * 32 + 48 - k0;          // xs row of w[0]
    #pragma unroll
    for (int jj = 0; jj < 47; ++jj) w[jj] = xs[(base + jj) * 64 + dl];
    #pragma unroll
    for (int k = k0; k < k0 + 16; ++k) {
      float kv = Ks[k * 64 + dl];
      #pragma unroll
      for (int t = 0; t < 32; ++t)
        acc[t] += kv * w[t + (k0 + 15 - k)];
    }
  }

  float* yb = yg + ((size_t)b * 4096 + t0 + g * 32) * 128 + d0 + dl;
  #pragma unroll
  for (int t = 0; t < 32; ++t)
    yb[(size_t)t * 128] = acc[t];
}

extern "C" void kernel_launch(void* const* d_in, const int* in_sizes, int n_in,
                              void* d_out, int out_size, void* d_ws, size_t ws_size,
                              hipStream_t stream) {
  const float* x = (const float*)d_in[0];
  const float* A = (const float*)d_in[1];
  const float* B = (const float*)d_in[2];
  const float* C = (const float*)d_in[3];
  float* y  = (float*)d_out;
  float* Kt = (float*)d_ws;   // 64*128*4 = 32 KB scratch

  s4_discretize<<<128, 256, 0, stream>>>(A, B, C, Kt);
  dim3 grid(32, 2, 16), block(64, 4);
  s4_conv<<<grid, block, 0, stream>>>(x, Kt, y);
}

// Round 4
// 124.587 us; speedup vs baseline: 2.5426x; 1.0767x over previous
//
#include <hip/hip_runtime.h>

typedef float f4 __attribute__((ext_vector_type(4)));

#define PAD 68          // row stride for 64x64 LDS matrices: keeps 16B align
#define ALPHA 0.29f     // 2/(lmin+lmax) for M = 4.2I - 0.05U, spectrum ~[2.6, 4.3]

// acc[m*4+c] = sum_n L[i0+m][n] * R[n][j0+c]   (row stride PAD)
__device__ __forceinline__ void mm_acc(const float* L, const float* R,
                                       int i0, int j0, float acc[16]) {
  #pragma unroll
  for (int m = 0; m < 16; ++m) acc[m] = 0.f;
  #pragma unroll
  for (int n = 0; n < 64; n += 4) {
    f4 La[4], Rb[4];
    #pragma unroll
    for (int m = 0; m < 4; ++m) La[m] = *(const f4*)&L[(i0 + m) * PAD + n];
    #pragma unroll
    for (int p = 0; p < 4; ++p) Rb[p] = *(const f4*)&R[(n + p) * PAD + j0];
    #pragma unroll
    for (int m = 0; m < 4; ++m)
      #pragma unroll
      for (int p = 0; p < 4; ++p)
        #pragma unroll
        for (int c = 0; c < 4; ++c)
          acc[m * 4 + c] += La[m][p] * Rb[p][c];
  }
}

// One block per channel d. K[k] = Cv . A_bar^k . B_bar via Newton inverse + power doubling.
// Writes K TRANSPOSED: Kout[k*128 + d].
__global__ __launch_bounds__(256) void s4_discretize(
    const float* __restrict__ Ag,   // (128,64,64)
    const float* __restrict__ Bg,   // (128,64)
    const float* __restrict__ Cg,   // (128,64)
    float* __restrict__ Kout)       // (64,128)
{
  __shared__ float Ms[64 * PAD];    // M, later A_bar
  __shared__ float Xs[64 * PAD];    // Newton iterate -> M^-1, later A_bar^4
  __shared__ float Ts[64 * PAD];    // temp, later A_bar^2
  __shared__ float C4[4][65];       // Cv . A_bar^j
  __shared__ float U16[64][16];     // A4^i . B_bar
  __shared__ float Bv[64], Cv0[64], Bb[64];
  __shared__ float Pr[4][64];

  const int d   = blockIdx.x;
  const int tid = threadIdx.x;
  const int i0  = (tid >> 4) << 2;  // output row tile
  const int j0  = (tid & 15) << 2;  // output col tile
  const int q   = tid >> 6;         // wave id 0..3
  const int ln  = tid & 63;

  // ---- load, build M = I - 0.05A and X1 = 2aI - a^2 M (one Newton step from aI) ----
  for (int idx = tid; idx < 4096; idx += 256) {
    int i = idx >> 6, j = idx & 63;
    float a = Ag[(size_t)d * 4096 + idx];
    float m = ((i == j) ? 1.f : 0.f) - 0.05f * a;
    Ms[i * PAD + j] = m;
    Xs[i * PAD + j] = ((i == j) ? 2.f * ALPHA : 0.f) - ALPHA * ALPHA * m;
  }
  if (tid < 64) { Bv[tid] = Bg[d * 64 + tid]; Cv0[tid] = Cg[d * 64 + tid]; }
  __syncthreads();

  // ---- 2 Newton iterations: X <- 2X - X(MX); residual (I-aM)^8 ~ 1.5e-5 ----
  float acc[16];
  for (int it = 0; it < 2; ++it) {
    mm_acc(Ms, Xs, i0, j0, acc);                // T = M X
    #pragma unroll
    for (int m = 0; m < 4; ++m) {
      f4 t = {acc[m*4+0], acc[m*4+1], acc[m*4+2], acc[m*4+3]};
      *(f4*)&Ts[(i0 + m) * PAD + j0] = t;
    }
    __syncthreads();
    mm_acc(Xs, Ts, i0, j0, acc);                // X T
    __syncthreads();                            // all reads of X done
    #pragma unroll
    for (int m = 0; m < 4; ++m) {
      f4 xo = *(const f4*)&Xs[(i0 + m) * PAD + j0];
      f4 t = {acc[m*4+0], acc[m*4+1], acc[m*4+2], acc[m*4+3]};
      *(f4*)&Xs[(i0 + m) * PAD + j0] = 2.f * xo - t;
    }
    __syncthreads();
  }
  // Xs = M^-1

  // ---- B_bar = 0.1 * X Bv ; A_bar = 2X - I -> Ms ----
  {
    float p = 0.f;
    #pragma unroll
    for (int m = 0; m < 16; ++m) p += Xs[ln * PAD + q * 16 + m] * Bv[q * 16 + m];
    Pr[q][ln] = p;
  }
  for (int idx = tid; idx < 4096; idx += 256) {
    int i = idx >> 6, j = idx & 63;
    Ms[i * PAD + j] = 2.f * Xs[i * PAD + j] - ((i == j) ? 1.f : 0.f);
  }
  __syncthreads();
  if (tid < 64) Bb[tid] = 0.1f * (Pr[0][tid] + Pr[1][tid] + Pr[2][tid] + Pr[3][tid]);
  __syncthreads();

  // ---- C chain: c_j = Cv . A_bar^j, j=0..3 ----
  if (tid < 64) C4[0][tid] = Cv0[tid];
  __syncthreads();
  for (int j = 1; j < 4; ++j) {
    float p = 0.f;
    #pragma unroll
    for (int m = 0; m < 16; ++m) p += C4[j - 1][q * 16 + m] * Ms[(q * 16 + m) * PAD + ln];
    Pr[q][ln] = p;
    __syncthreads();
    if (q == 0) C4[j][ln] = Pr[0][ln] + Pr[1][ln] + Pr[2][ln] + Pr[3][ln];
    __syncthreads();
  }

  // ---- A^2 -> Ts ; A^4 -> Xs ----
  mm_acc(Ms, Ms, i0, j0, acc);
  #pragma unroll
  for (int m = 0; m < 4; ++m) {
    f4 t = {acc[m*4+0], acc[m*4+1], acc[m*4+2], acc[m*4+3]};
    *(f4*)&Ts[(i0 + m) * PAD + j0] = t;
  }
  __syncthreads();
  mm_acc(Ts, Ts, i0, j0, acc);
  __syncthreads();
  #pragma unroll
  for (int m = 0; m < 4; ++m) {
    f4 t = {acc[m*4+0], acc[m*4+1], acc[m*4+2], acc[m*4+3]};
    *(f4*)&Xs[(i0 + m) * PAD + j0] = t;
  }
  __syncthreads();

  // ---- U chain: u_i = A4^i . B_bar, i=0..15 ----
  if (tid < 64) U16[tid][0] = Bb[tid];
  __syncthreads();
  for (int i = 1; i < 16; ++i) {
    float p = 0.f;
    #pragma unroll
    for (int m = 0; m < 16; ++m) p += Xs[ln * PAD + q * 16 + m] * U16[q * 16 + m][i - 1];
    Pr[q][ln] = p;
    __syncthreads();
    if (q == 0) U16[ln][i] = Pr[0][ln] + Pr[1][ln] + Pr[2][ln] + Pr[3][ln];
    __syncthreads();
  }

  // ---- K[k] = c_{k&3} . u_{k>>2}, write transposed ----
  if (tid < 64) {
    int i = tid >> 2, j = tid & 3;
    float s = 0.f;
    #pragma unroll
    for (int n = 0; n < 64; ++n) s += C4[j][n] * U16[n][i];
    Kout[tid * 128 + d] = s;
  }
}

// Depthwise causal conv, 64 taps. Block: 32 d x 256 t tile; thread = (dl, g) does 32 t.
// LDS 49 KB -> 3 blocks/CU (12 waves) for latency hiding; halo ratio 319/256 = 1.25x.
__global__ __launch_bounds__(256) void s4_conv(
    const float* __restrict__ xg,   // (16,4096,128)
    const float* __restrict__ Ktg,  // (64,128) transposed K
    float* __restrict__ yg)         // (16,4096,128)
{
  __shared__ float xs[319 * 32];    // 40,832 B
  __shared__ float Ks[64 * 32];     //  8,192 B

  const int tid = threadIdx.y * 32 + threadIdx.x;
  const int tc  = blockIdx.x;       // t chunk (256 t each)
  const int dq  = blockIdx.y;       // d quarter
  const int b   = blockIdx.z;
  const int d0  = dq * 32;
  const int t0  = tc * 256;

  // stage K quarter: Ks[k*32+dl] = Kt[k][d0+dl]
  for (int idx = tid; idx < 2048; idx += 256)
    Ks[idx] = Ktg[(idx >> 5) * 128 + d0 + (idx & 31)];

  // stage x rows t0-63 .. t0+255 (319 rows x 32 floats), float4
  const float* xb = xg + (size_t)b * 4096 * 128 + d0;
  for (int idx = tid; idx < 319 * 8; idx += 256) {
    int row = idx >> 3, c4 = (idx & 7) << 2;
    int t = t0 - 63 + row;
    f4 v = {0.f, 0.f, 0.f, 0.f};
    if (t >= 0) v = *(const f4*)&xb[(size_t)t * 128 + c4];
    *(f4*)&xs[row * 32 + c4] = v;
  }
  __syncthreads();

  const int dl = threadIdx.x;
  const int g  = threadIdx.y;

  float acc[32];
  #pragma unroll
  for (int t = 0; t < 32; ++t) acc[t] = 0.f;

  float w[47];
  #pragma unroll
  for (int k0 = 0; k0 < 64; k0 += 16) {
    const int base = g * 32 + 48 - k0;          // xs row of w[0]
    #pragma unroll
    for (int jj = 0; jj < 47; ++jj) w[jj] = xs[(base + jj) * 32 + dl];
    #pragma unroll
    for (int k = k0; k < k0 + 16; ++k) {
      float kv = Ks[k * 32 + dl];
      #pragma unroll
      for (int t = 0; t < 32; ++t)
        acc[t] += kv * w[t + (k0 + 15 - k)];
    }
  }

  float* yb = yg + ((size_t)b * 4096 + t0 + g * 32) * 128 + d0 + dl;
  #pragma unroll
  for (int t = 0; t < 32; ++t)
    yb[(size_t)t * 128] = acc[t];
}

extern "C" void kernel_launch(void* const* d_in, const int* in_sizes, int n_in,
                              void* d_out, int out_size, void* d_ws, size_t ws_size,
                              hipStream_t stream) {
  const float* x = (const float*)d_in[0];
  const float* A = (const float*)d_in[1];
  const float* B = (const float*)d_in[2];
  const float* C = (const float*)d_in[3];
  float* y  = (float*)d_out;
  float* Kt = (float*)d_ws;   // 64*128*4 = 32 KB scratch

  s4_discretize<<<128, 256, 0, stream>>>(A, B, C, Kt);
  dim3 grid(16, 4, 16), block(32, 8);
  s4_conv<<<grid, block, 0, stream>>>(x, Kt, y);
}